// Round 13
// baseline (180.970 us; speedup 1.0000x reference)
//
#include <hip/hip_runtime.h>
#include <math.h>

// SemanticDriftCoeff — band+prefix, v5: MFMA band kernel with transposed-h
// B-operands (vector frag loads replace R12's scalar gathers).
// w(t,s) == 1.0 exactly in bf16 for dt >= 32 (HW-verified R9-R12), so
//   g_acc(t) = P(t-32) + W_band(t,:) · H_window,  L(t) = (t-31)_+ + sum w
// hbTp = h^T with 32 zero cols in front (stride T+64): band B-frags are
// contiguous 16B loads; s<0 / tail reads hit zeros/finite poison x w=0.
// k_gemm3 (cross = g h^T causal row-max) byte-identical to R12.
// ws: invnorm[T], dmaxu[T], gn2[T], dist2[T], Sseg[64D], Eseg[64D], P[T*D] f32;
// hb[T*D], hbTp[D*(T+64)], gb[T*D] bf16. ~37 MB.

#define T_ 4096
#define D_ 896
#define TP (T_ + 64)   // padded hbTp row stride (ushorts)

typedef float f32x4 __attribute__((ext_vector_type(4)));
typedef unsigned short u16x8 __attribute__((ext_vector_type(8)));
typedef __bf16 bf16x8 __attribute__((ext_vector_type(8)));

union V16 { uint4 u; u16x8 v; };

__device__ __forceinline__ u16x8 ld16(const unsigned short* p) {
  V16 x; x.u = *(const uint4*)p; return x.v;
}
__device__ __forceinline__ unsigned short f2bf(float f) {  // RNE float->bf16 bits
  unsigned int u = __float_as_uint(f);
  u += 0x7FFFu + ((u >> 16) & 1u);
  return (unsigned short)(u >> 16);
}
__device__ __forceinline__ float bf2f(unsigned short b) {
  return __uint_as_float(((unsigned int)b) << 16);
}
__device__ __forceinline__ float4 bf4f(uint2 u) {
  return make_float4(bf2f((unsigned short)(u.x & 0xffff)),
                     bf2f((unsigned short)(u.x >> 16)),
                     bf2f((unsigned short)(u.y & 0xffff)),
                     bf2f((unsigned short)(u.y >> 16)));
}
__device__ __forceinline__ f32x4 mfma16(u16x8 a, u16x8 b, f32x4 c) {
  return __builtin_amdgcn_mfma_f32_16x16x32_bf16(
      __builtin_bit_cast(bf16x8, a), __builtin_bit_cast(bf16x8, b), c, 0, 0, 0);
}

typedef __attribute__((address_space(1))) const void glob_cv;
typedef __attribute__((address_space(3))) void lds_v;
__device__ __forceinline__ void gload16(const void* g, void* l) {
  __builtin_amdgcn_global_load_lds((glob_cv*)g, (lds_v*)l, 16, 0, 0);
}

// 128x128 bf16 tile stage with XOR group swizzle (R7, 0 bank conflicts).
__device__ __forceinline__ void stage_sw(const unsigned short* __restrict__ g0,
                                         int stride, unsigned short* lds0, int tid) {
  #pragma unroll
  for (int it = 0; it < 8; ++it) {
    const int e = it * 256 + tid;
    const int row = e >> 4, pg = e & 15;
    const int gg = pg ^ (row & 15);
    gload16(g0 + (size_t)row * stride + gg * 8, lds0 + e * 8);
  }
}

__device__ __forceinline__ void mfma_chunk(const unsigned short* As,
    const unsigned short* Bs, int wm, int wn, int tcol, int quad, f32x4 acc[4][4]) {
  const int sx = tcol & 15;
  #pragma unroll
  for (int kk = 0; kk < 4; ++kk) {
    u16x8 af[4], bf[4];
    const int go = ((kk * 4 + quad) ^ sx) * 8;
    #pragma unroll
    for (int mi = 0; mi < 4; ++mi)
      af[mi] = ld16(&As[(wm * 64 + mi * 16 + tcol) * 128 + go]);
    #pragma unroll
    for (int ni = 0; ni < 4; ++ni)
      bf[ni] = ld16(&Bs[(wn * 64 + ni * 16 + tcol) * 128 + go]);
    #pragma unroll
    for (int mi = 0; mi < 4; ++mi)
      #pragma unroll
      for (int ni = 0; ni < 4; ++ni)
        acc[mi][ni] = mfma16(af[mi], bf[ni], acc[mi][ni]);
  }
}

__device__ __forceinline__ void tri_decode(int b, int& ti, int& sj) {
  ti = (int)((sqrtf(8.0f * (float)b + 1.0f) - 1.0f) * 0.5f);
  while ((ti + 1) * (ti + 2) / 2 <= b) ++ti;
  while (ti * (ti + 1) / 2 > b) --ti;
  sj = b - ti * (ti + 1) / 2;
}

// ---------- prep: invnorm + bf16 normalized rows ----------
__global__ __launch_bounds__(256) void k_prep(const float* __restrict__ x,
    float* __restrict__ invnorm, unsigned short* __restrict__ hb) {
  const int t = (int)blockIdx.x, tid = (int)threadIdx.x;
  const int c = tid * 4;
  float4 v = make_float4(0.f, 0.f, 0.f, 0.f);
  float s = 0.f;
  if (c < D_) {
    v = *(const float4*)(x + (size_t)t * D_ + c);
    s = v.x * v.x + v.y * v.y + v.z * v.z + v.w * v.w;
  }
  __shared__ float sb[4];
  __shared__ float sinv;
  #pragma unroll
  for (int off = 32; off > 0; off >>= 1) s += __shfl_down(s, off, 64);
  if ((tid & 63) == 0) sb[tid >> 6] = s;
  __syncthreads();
  if (tid == 0) {
    const float tot = sb[0] + sb[1] + sb[2] + sb[3];
    const float iv = 1.0f / fmaxf(sqrtf(tot), 1e-12f);
    invnorm[t] = iv; sinv = iv;
  }
  __syncthreads();
  if (c < D_) {
    const float iv = sinv;
    *(ushort4*)(hb + (size_t)t * D_ + c) = make_ushort4(
        f2bf(v.x * iv), f2bf(v.y * iv), f2bf(v.z * iv), f2bf(v.w * iv));
  }
}

// ---------- 32x32 transpose hb -> hbTp (data at col offset 32, front zeroed) ----------
__global__ __launch_bounds__(256) void k_transp(const unsigned short* __restrict__ hb,
                                                unsigned short* __restrict__ hbTp) {
  __shared__ unsigned short Ts[32][36];
  const int t0 = (int)blockIdx.x * 32, d0 = (int)blockIdx.y * 32;
  const int r = (int)threadIdx.x >> 3, c = ((int)threadIdx.x & 7) * 4;
  const ushort4 v = *(const ushort4*)(hb + (size_t)(t0 + r) * D_ + d0 + c);
  Ts[r][c] = v.x; Ts[r][c + 1] = v.y; Ts[r][c + 2] = v.z; Ts[r][c + 3] = v.w;
  __syncthreads();
  const ushort4 o = make_ushort4(Ts[c][r], Ts[c + 1][r], Ts[c + 2][r], Ts[c + 3][r]);
  *(ushort4*)(hbTp + (size_t)(d0 + r) * TP + 32 + t0 + c) = o;
  if (blockIdx.x == 0)   // zero the 32 leading pad cols for these 32 d rows
    *(ushort4*)(hbTp + (size_t)(d0 + r) * TP + c) = make_ushort4(0, 0, 0, 0);
}

// ---------- prefix scan of hb rows (fp32) ----------
__global__ __launch_bounds__(64) void k_sega(const unsigned short* __restrict__ hb,
                                             float* __restrict__ Sseg) {
  const int seg = (int)blockIdx.x, tid = (int)threadIdx.x;
  if (tid >= 56) return;
  const int c = (int)blockIdx.y * 224 + tid * 4;
  float4 acc = make_float4(0.f, 0.f, 0.f, 0.f);
  for (int r = 0; r < 64; ++r) {
    const float4 h = bf4f(*(const uint2*)(hb + (size_t)(seg * 64 + r) * D_ + c));
    acc.x += h.x; acc.y += h.y; acc.z += h.z; acc.w += h.w;
  }
  *(float4*)(Sseg + (size_t)seg * D_ + c) = acc;
}

// wave-scan over the 64 segments: lane = seg, one column per wave
__global__ __launch_bounds__(256) void k_segb(const float* __restrict__ Sseg,
                                              float* __restrict__ Eseg) {
  const int tid = (int)threadIdx.x;
  const int wv = tid >> 6, lane = tid & 63;
  const int c = (int)blockIdx.x * 4 + wv;     // column 0..895
  float v = Sseg[(size_t)lane * D_ + c];
  const float orig = v;
  #pragma unroll
  for (int off = 1; off < 64; off <<= 1) {
    const float n = __shfl_up(v, off, 64);
    if (lane >= off) v += n;
  }
  Eseg[(size_t)lane * D_ + c] = v - orig;     // exclusive
}

__global__ __launch_bounds__(64) void k_segc(const unsigned short* __restrict__ hb,
    const float* __restrict__ Eseg, float* __restrict__ P) {
  const int seg = (int)blockIdx.x, tid = (int)threadIdx.x;
  if (tid >= 56) return;
  const int c = (int)blockIdx.y * 224 + tid * 4;
  float4 run = *(const float4*)(Eseg + (size_t)seg * D_ + c);
  for (int r = 0; r < 64; ++r) {
    const int row = seg * 64 + r;
    const float4 h = bf4f(*(const uint2*)(hb + (size_t)row * D_ + c));
    run.x += h.x; run.y += h.y; run.z += h.z; run.w += h.w;
    *(float4*)(P + (size_t)row * D_ + c) = run;      // inclusive P(row)
  }
}

// ---------- fused band kernel: sims -> weights(A-frag) -> band GEMM -> epilogue ----
// Block = 16 t's. Window cols k = s-(t0-32), k in [0,64); A[t][k]=w (0 outside band).
__global__ __launch_bounds__(256) void k_band(const unsigned short* __restrict__ hb,
    const unsigned short* __restrict__ hbTp, const float* __restrict__ P,
    const float* __restrict__ x, const float* __restrict__ invnorm,
    unsigned short* __restrict__ gb, float* __restrict__ gn2,
    float* __restrict__ dist2) {
  const int t0 = (int)blockIdx.x * 16;
  const int tid = (int)threadIdx.x;
  const int wv = tid >> 6, lane = tid & 63;
  const int tcol = lane & 15, quad = lane >> 4;
  __shared__ float sims[16][52];       // [t_local][k], padded stride
  __shared__ float invLs[16];
  __shared__ float red1[4][16], red2[4][16];

  // phase 1: three 16x16 diagonal sim tiles (R10-verified)
  if (wv < 3) {
    const int s_base = t0 - 32 + wv * 16;
    if (s_base + 15 >= 0) {
      const int srow = max(s_base + tcol, 0);   // clamped; guarded in phase 2
      f32x4 acc = {};
      const unsigned short* arow = hb + (size_t)srow * D_ + quad * 8;
      const unsigned short* brow = hb + (size_t)(t0 + tcol) * D_ + quad * 8;
      #pragma unroll
      for (int kc = 0; kc < 28; ++kc)
        acc = mfma16(ld16(arow + kc * 32), ld16(brow + kc * 32), acc);
      #pragma unroll
      for (int r = 0; r < 4; ++r)       // C[m=s_local=quad*4+r][n=t_local=tcol]
        sims[tcol][wv * 16 + quad * 4 + r] = acc[r];
    }
  }
  __syncthreads();

  // phase 2: weights in A-frag layout (A[m=tcol][k=quad*8+j]) + L
  u16x8 af0, af1;
  float lsum = 0.f;
  #pragma unroll
  for (int j = 0; j < 8; ++j) {
    {
      const int k = quad * 8 + j;                 // k in [0,32)
      const int dt = tcol + 32 - k;               // >= 1
      const int s = t0 - 32 + k;
      unsigned short wb = 0;
      if (dt < 32 && s >= 0)
        wb = f2bf(__expf(sims[tcol][k] * (__expf(-0.1f * (float)dt) * 0.033407657f)));
      af0[j] = wb;
      lsum += bf2f(wb);
    }
    {
      const int k = 32 + quad * 8 + j;            // k in [32,64)
      const int dt = tcol + 32 - k;               // <= 15
      unsigned short wb = 0;
      if (dt >= 0)                                // k <= tcol+32 <= 47
        wb = f2bf(__expf(sims[tcol][k] * (__expf(-0.1f * (float)dt) * 0.033407657f)));
      af1[j] = wb;
      lsum += bf2f(wb);
    }
  }
  lsum += __shfl_xor(lsum, 16, 64);
  lsum += __shfl_xor(lsum, 32, 64);
  if (wv == 0 && lane < 16) {
    const int t = t0 + lane;
    invLs[lane] = 1.0f / (lsum + ((t >= 32) ? (float)(t - 31) : 0.f));
  }
  __syncthreads();

  // phase 3: band GEMM over 56 d-tiles (14 per wave), B-frags from hbTp.
  // Window col index in hbTp = 32 + (t0-32) + k = t0 + k (16B-aligned loads).
  float invLr[4], inrr[4];
  #pragma unroll
  for (int r = 0; r < 4; ++r) {
    invLr[r] = invLs[quad * 4 + r];
    inrr[r]  = invnorm[t0 + quad * 4 + r];
  }
  float sgl[4] = {0.f, 0.f, 0.f, 0.f}, sdl[4] = {0.f, 0.f, 0.f, 0.f};
  for (int nt = 0; nt < 14; ++nt) {
    const int d = (wv * 14 + nt) * 16 + tcol;
    const unsigned short* brow = hbTp + (size_t)d * TP + t0 + quad * 8;
    const u16x8 b0 = ld16(brow);          // k in [0,32): zeros where s<0
    const u16x8 b1 = ld16(brow + 32);     // k in [32,64): tail x w=0 harmless
    f32x4 C = {};
    C = mfma16(af0, b0, C);
    C = mfma16(af1, b1, C);
    #pragma unroll
    for (int r = 0; r < 4; ++r) {     // C[m=quad*4+r -> t][n=tcol -> d]
      const int tt = t0 + quad * 4 + r;
      float gacc = C[r];
      if (tt >= 32) gacc += P[(size_t)(tt - 32) * D_ + d];
      const float g = gacc * invLr[r];
      gb[(size_t)tt * D_ + d] = f2bf(g);
      const float e = x[(size_t)tt * D_ + d] * inrr[r] - g;
      sgl[r] += g * g;
      sdl[r] += e * e;
    }
  }
  #pragma unroll
  for (int r = 0; r < 4; ++r) {
    float sg = sgl[r], sd = sdl[r];
    sg += __shfl_xor(sg, 1, 64); sg += __shfl_xor(sg, 2, 64);
    sg += __shfl_xor(sg, 4, 64); sg += __shfl_xor(sg, 8, 64);
    sd += __shfl_xor(sd, 1, 64); sd += __shfl_xor(sd, 2, 64);
    sd += __shfl_xor(sd, 4, 64); sd += __shfl_xor(sd, 8, 64);
    if (tcol == 0) { red1[wv][quad * 4 + r] = sg; red2[wv][quad * 4 + r] = sd; }
  }
  __syncthreads();
  if (tid < 16) {
    gn2[t0 + tid]   = red1[0][tid] + red1[1][tid] + red1[2][tid] + red1[3][tid];
    dist2[t0 + tid] = red2[0][tid] + red2[1][tid] + red2[2][tid] + red2[3][tid];
  }
}

// ---------- GEMM3: cross = g h^T (528 causal 128x128 tiles, BK=128); row-max ----------
__global__ __launch_bounds__(256, 2) void k_gemm3(const unsigned short* __restrict__ gb,
    const unsigned short* __restrict__ hb, const float* __restrict__ gn2,
    unsigned int* __restrict__ dmaxu) {
  int ti, sj;
  tri_decode((int)blockIdx.x, ti, sj);
  const int t0 = ti * 128, s0 = sj * 128;
  __shared__ unsigned short As[128 * 128];
  __shared__ unsigned short Bs[128 * 128];
  const int tid = (int)threadIdx.x;
  const int lane = tid & 63, wv = tid >> 6;
  const int wm = wv >> 1, wn = wv & 1;
  const int tcol = lane & 15, quad = lane >> 4;
  f32x4 acc[4][4] = {};
  for (int kc = 0; kc < 7; ++kc) {
    __syncthreads();
    stage_sw(gb + (size_t)t0 * D_ + kc * 128, D_, As, tid);
    stage_sw(hb + (size_t)s0 * D_ + kc * 128, D_, Bs, tid);
    __syncthreads();
    mfma_chunk(As, Bs, wm, wn, tcol, quad, acc);
  }
  #pragma unroll
  for (int mi = 0; mi < 4; ++mi) {
    #pragma unroll
    for (int r = 0; r < 4; ++r) {
      const int t = t0 + wm * 64 + mi * 16 + quad * 4 + r;
      const float gn = gn2[t];
      float m2 = 0.f;
      #pragma unroll
      for (int ni = 0; ni < 4; ++ni) {
        const int s = s0 + wn * 64 + ni * 16 + tcol;
        if (t - s >= 0)
          m2 = fmaxf(m2, fmaxf(1.0f - 2.0f * acc[mi][ni][r] + gn, 1e-24f));
      }
      m2 = fmaxf(m2, __shfl_xor(m2, 1, 64));
      m2 = fmaxf(m2, __shfl_xor(m2, 2, 64));
      m2 = fmaxf(m2, __shfl_xor(m2, 4, 64));
      m2 = fmaxf(m2, __shfl_xor(m2, 8, 64));
      if (tcol == 0) atomicMax(&dmaxu[t], __float_as_uint(m2));
    }
  }
}

__global__ __launch_bounds__(256) void k_final(const float* __restrict__ m_t,
    const float* __restrict__ c_t, const float* __restrict__ d_t,
    const float* __restrict__ mu, const float* __restrict__ dist2,
    const unsigned int* __restrict__ dmaxu, float* __restrict__ out) {
  const int t = (int)blockIdx.x * 256 + (int)threadIdx.x;
  if (t >= T_) return;
  float ratio;
  if (t == 0) {
    ratio = 0.f;  // ref: dist~1e-12, dist_max<1e-6 -> 1.0 => ratio ~0
  } else {
    float dmax = sqrtf(__uint_as_float(dmaxu[t]));
    if (dmax < 1e-6f) dmax = 1.0f;
    ratio = sqrtf(fmaxf(dist2[t], 1e-24f)) / (dmax + 1e-8f);
  }
  const float stab = 1.0f - 0.3f * c_t[t] + 0.2f * d_t[t];
  const float xi = 1.0f - mu[0] * m_t[t];
  out[t] = fminf(fmaxf(ratio * stab * xi, 0.f), 1.f);
}

extern "C" void kernel_launch(void* const* d_in, const int* in_sizes, int n_in,
                              void* d_out, int out_size, void* d_ws, size_t ws_size,
                              hipStream_t stream) {
  const float* x   = (const float*)d_in[0];
  const float* m_t = (const float*)d_in[1];
  const float* c_t = (const float*)d_in[2];
  const float* d_t = (const float*)d_in[3];
  const float* mu  = (const float*)d_in[4];
  float* out = (float*)d_out;

  float* ws = (float*)d_ws;
  float* invnorm = ws;                                          // [T]
  unsigned int* dmaxu = (unsigned int*)(ws + (size_t)T_);       // [T]
  float* gn2     = ws + 2 * (size_t)T_;                         // [T]
  float* dist2   = ws + 3 * (size_t)T_;                         // [T]
  float* Sseg    = ws + 4 * (size_t)T_;                         // [64*D]
  float* Eseg    = Sseg + 64 * (size_t)D_;                      // [64*D]
  float* P       = Eseg + 64 * (size_t)D_;                      // [T*D] fp32
  unsigned short* hb   = (unsigned short*)(P + (size_t)T_ * D_);  // [T*D]
  unsigned short* hbTp = hb + (size_t)T_ * D_;                    // [D*(T+64)]
  unsigned short* gb   = hbTp + (size_t)D_ * TP;                  // [T*D]

  hipMemsetAsync(dmaxu, 0, (size_t)T_ * sizeof(unsigned int), stream);

  k_prep<<<T_, 256, 0, stream>>>(x, invnorm, hb);
  k_transp<<<dim3(T_ / 32, D_ / 32), 256, 0, stream>>>(hb, hbTp);
  k_sega<<<dim3(64, 4), 64, 0, stream>>>(hb, Sseg);
  k_segb<<<224, 256, 0, stream>>>(Sseg, Eseg);
  k_segc<<<dim3(64, 4), 64, 0, stream>>>(hb, Eseg, P);
  k_band<<<T_ / 16, 256, 0, stream>>>(hb, hbTp, P, x, invnorm, gb, gn2, dist2);
  k_gemm3<<<528, 256, 0, stream>>>(gb, hb, gn2, dmaxu);
  k_final<<<(T_ + 255) / 256, 256, 0, stream>>>(m_t, c_t, d_t, mu, dist2, dmaxu, out);
}

// Round 14
// 160.617 us; speedup vs baseline: 1.1267x; 1.1267x over previous
//
#include <hip/hip_runtime.h>
#include <math.h>

// SemanticDriftCoeff — band+prefix, v6: split band kernels (bandw/bandg),
// deep-MLP sim loads, 2048-block band GEMM, re-segmented scan (128x32).
// w(t,s) == 1.0 exactly in bf16 for dt >= 32 (HW-verified R9-R13), so
//   g_acc(t) = P(t-32) + W_band(t,:) · H_window,  L(t) = (t-31)_+ + sum w
// k_gemm3 (cross = g h^T causal row-max) byte-identical to R13.
// ws: invnorm[T], dmaxu[T], gn2[T], dist2[T], invLb[T], Sseg[128*D],
// Eseg[128*D], P[T*D] f32; hb[T*D], hbTp[D*(T+64)], gb[T*D], wband[T*64] bf16.

#define T_ 4096
#define D_ 896
#define TP (T_ + 64)   // padded hbTp row stride (ushorts)

typedef float f32x4 __attribute__((ext_vector_type(4)));
typedef unsigned short u16x8 __attribute__((ext_vector_type(8)));
typedef __bf16 bf16x8 __attribute__((ext_vector_type(8)));

union V16 { uint4 u; u16x8 v; };

__device__ __forceinline__ u16x8 ld16(const unsigned short* p) {
  V16 x; x.u = *(const uint4*)p; return x.v;
}
__device__ __forceinline__ void st16(unsigned short* p, u16x8 v) {
  V16 x; x.v = v; *(uint4*)p = x.u;
}
__device__ __forceinline__ unsigned short f2bf(float f) {  // RNE float->bf16 bits
  unsigned int u = __float_as_uint(f);
  u += 0x7FFFu + ((u >> 16) & 1u);
  return (unsigned short)(u >> 16);
}
__device__ __forceinline__ float bf2f(unsigned short b) {
  return __uint_as_float(((unsigned int)b) << 16);
}
__device__ __forceinline__ float4 bf4f(uint2 u) {
  return make_float4(bf2f((unsigned short)(u.x & 0xffff)),
                     bf2f((unsigned short)(u.x >> 16)),
                     bf2f((unsigned short)(u.y & 0xffff)),
                     bf2f((unsigned short)(u.y >> 16)));
}
__device__ __forceinline__ f32x4 mfma16(u16x8 a, u16x8 b, f32x4 c) {
  return __builtin_amdgcn_mfma_f32_16x16x32_bf16(
      __builtin_bit_cast(bf16x8, a), __builtin_bit_cast(bf16x8, b), c, 0, 0, 0);
}

typedef __attribute__((address_space(1))) const void glob_cv;
typedef __attribute__((address_space(3))) void lds_v;
__device__ __forceinline__ void gload16(const void* g, void* l) {
  __builtin_amdgcn_global_load_lds((glob_cv*)g, (lds_v*)l, 16, 0, 0);
}

// 128x128 bf16 tile stage with XOR group swizzle (R7, 0 bank conflicts).
__device__ __forceinline__ void stage_sw(const unsigned short* __restrict__ g0,
                                         int stride, unsigned short* lds0, int tid) {
  #pragma unroll
  for (int it = 0; it < 8; ++it) {
    const int e = it * 256 + tid;
    const int row = e >> 4, pg = e & 15;
    const int gg = pg ^ (row & 15);
    gload16(g0 + (size_t)row * stride + gg * 8, lds0 + e * 8);
  }
}

__device__ __forceinline__ void mfma_chunk(const unsigned short* As,
    const unsigned short* Bs, int wm, int wn, int tcol, int quad, f32x4 acc[4][4]) {
  const int sx = tcol & 15;
  #pragma unroll
  for (int kk = 0; kk < 4; ++kk) {
    u16x8 af[4], bf[4];
    const int go = ((kk * 4 + quad) ^ sx) * 8;
    #pragma unroll
    for (int mi = 0; mi < 4; ++mi)
      af[mi] = ld16(&As[(wm * 64 + mi * 16 + tcol) * 128 + go]);
    #pragma unroll
    for (int ni = 0; ni < 4; ++ni)
      bf[ni] = ld16(&Bs[(wn * 64 + ni * 16 + tcol) * 128 + go]);
    #pragma unroll
    for (int mi = 0; mi < 4; ++mi)
      #pragma unroll
      for (int ni = 0; ni < 4; ++ni)
        acc[mi][ni] = mfma16(af[mi], bf[ni], acc[mi][ni]);
  }
}

__device__ __forceinline__ void tri_decode(int b, int& ti, int& sj) {
  ti = (int)((sqrtf(8.0f * (float)b + 1.0f) - 1.0f) * 0.5f);
  while ((ti + 1) * (ti + 2) / 2 <= b) ++ti;
  while (ti * (ti + 1) / 2 > b) --ti;
  sj = b - ti * (ti + 1) / 2;
}

// ---------- prep: invnorm + bf16 normalized rows ----------
__global__ __launch_bounds__(256) void k_prep(const float* __restrict__ x,
    float* __restrict__ invnorm, unsigned short* __restrict__ hb) {
  const int t = (int)blockIdx.x, tid = (int)threadIdx.x;
  const int c = tid * 4;
  float4 v = make_float4(0.f, 0.f, 0.f, 0.f);
  float s = 0.f;
  if (c < D_) {
    v = *(const float4*)(x + (size_t)t * D_ + c);
    s = v.x * v.x + v.y * v.y + v.z * v.z + v.w * v.w;
  }
  __shared__ float sb[4];
  __shared__ float sinv;
  #pragma unroll
  for (int off = 32; off > 0; off >>= 1) s += __shfl_down(s, off, 64);
  if ((tid & 63) == 0) sb[tid >> 6] = s;
  __syncthreads();
  if (tid == 0) {
    const float tot = sb[0] + sb[1] + sb[2] + sb[3];
    const float iv = 1.0f / fmaxf(sqrtf(tot), 1e-12f);
    invnorm[t] = iv; sinv = iv;
  }
  __syncthreads();
  if (c < D_) {
    const float iv = sinv;
    *(ushort4*)(hb + (size_t)t * D_ + c) = make_ushort4(
        f2bf(v.x * iv), f2bf(v.y * iv), f2bf(v.z * iv), f2bf(v.w * iv));
  }
}

// ---------- 32x32 transpose hb -> hbTp (data at col offset 32, front zeroed) ----------
__global__ __launch_bounds__(256) void k_transp(const unsigned short* __restrict__ hb,
                                                unsigned short* __restrict__ hbTp) {
  __shared__ unsigned short Ts[32][36];
  const int t0 = (int)blockIdx.x * 32, d0 = (int)blockIdx.y * 32;
  const int r = (int)threadIdx.x >> 3, c = ((int)threadIdx.x & 7) * 4;
  const ushort4 v = *(const ushort4*)(hb + (size_t)(t0 + r) * D_ + d0 + c);
  Ts[r][c] = v.x; Ts[r][c + 1] = v.y; Ts[r][c + 2] = v.z; Ts[r][c + 3] = v.w;
  __syncthreads();
  const ushort4 o = make_ushort4(Ts[c][r], Ts[c + 1][r], Ts[c + 2][r], Ts[c + 3][r]);
  *(ushort4*)(hbTp + (size_t)(d0 + r) * TP + 32 + t0 + c) = o;
  if (blockIdx.x == 0)   // zero the 32 leading pad cols for these 32 d rows
    *(ushort4*)(hbTp + (size_t)(d0 + r) * TP + c) = make_ushort4(0, 0, 0, 0);
}

// ---------- scan: 128 segments x 32 rows ----------
__global__ __launch_bounds__(256) void k_sega(const unsigned short* __restrict__ hb,
                                              float* __restrict__ Sseg) {
  const int seg = (int)blockIdx.x, tid = (int)threadIdx.x;
  const int wv = tid >> 6, lane = tid & 63;
  __shared__ float4 part[4][56];
  const int c = (int)blockIdx.y * 224 + lane * 4;
  float4 acc = make_float4(0.f, 0.f, 0.f, 0.f);
  if (lane < 56) {
    #pragma unroll
    for (int r = 0; r < 8; ++r) {
      const int row = seg * 32 + wv * 8 + r;
      const float4 h = bf4f(*(const uint2*)(hb + (size_t)row * D_ + c));
      acc.x += h.x; acc.y += h.y; acc.z += h.z; acc.w += h.w;
    }
    part[wv][lane] = acc;
  }
  __syncthreads();
  if (wv == 0 && lane < 56) {
    const float4 a = part[0][lane], b = part[1][lane];
    const float4 d = part[2][lane], e = part[3][lane];
    *(float4*)(Sseg + (size_t)seg * D_ + c) = make_float4(
        a.x + b.x + d.x + e.x, a.y + b.y + d.y + e.y,
        a.z + b.z + d.z + e.z, a.w + b.w + d.w + e.w);
  }
}

// wave-scan of 128 segments (2x64 per lane) — one column per wave
__global__ __launch_bounds__(256) void k_segb(const float* __restrict__ Sseg,
                                              float* __restrict__ Eseg) {
  const int tid = (int)threadIdx.x;
  const int wv = tid >> 6, lane = tid & 63;
  const int c = (int)blockIdx.x * 4 + wv;     // column 0..895
  float v0 = Sseg[(size_t)lane * D_ + c];
  float v1 = Sseg[(size_t)(64 + lane) * D_ + c];
  const float o0 = v0, o1 = v1;
  #pragma unroll
  for (int off = 1; off < 64; off <<= 1) {
    const float n0 = __shfl_up(v0, off, 64);
    const float n1 = __shfl_up(v1, off, 64);
    if (lane >= off) { v0 += n0; v1 += n1; }
  }
  const float tot0 = __shfl(v0, 63, 64);
  Eseg[(size_t)lane * D_ + c] = v0 - o0;              // exclusive
  Eseg[(size_t)(64 + lane) * D_ + c] = v1 - o1 + tot0;
}

__global__ __launch_bounds__(64) void k_segc(const unsigned short* __restrict__ hb,
    const float* __restrict__ Eseg, float* __restrict__ P) {
  const int seg = (int)blockIdx.x, tid = (int)threadIdx.x;
  if (tid >= 56) return;
  const int c = (int)blockIdx.y * 224 + tid * 4;
  float4 run = *(const float4*)(Eseg + (size_t)seg * D_ + c);
  for (int r = 0; r < 32; ++r) {
    const int row = seg * 32 + r;
    const float4 h = bf4f(*(const uint2*)(hb + (size_t)row * D_ + c));
    run.x += h.x; run.y += h.y; run.z += h.z; run.w += h.w;
    *(float4*)(P + (size_t)row * D_ + c) = run;      // inclusive P(row)
  }
}

// ---------- bandw: diagonal sims (deep-MLP loads) -> weights + invL ----------
__global__ __launch_bounds__(256) void k_bandw(const unsigned short* __restrict__ hb,
    unsigned short* __restrict__ wband, float* __restrict__ invLb) {
  const int t0 = (int)blockIdx.x * 16;
  const int tid = (int)threadIdx.x;
  const int wv = tid >> 6, lane = tid & 63;
  const int tcol = lane & 15, quad = lane >> 4;
  __shared__ float sims[16][52];
  if (wv < 3) {
    const int s_base = t0 - 32 + wv * 16;
    if (s_base + 15 >= 0) {
      const int srow = max(s_base + tcol, 0);   // clamped; guarded below
      f32x4 acc = {};
      const unsigned short* arow = hb + (size_t)srow * D_ + quad * 8;
      const unsigned short* brow = hb + (size_t)(t0 + tcol) * D_ + quad * 8;
      #pragma unroll 1
      for (int c4 = 0; c4 < 4; ++c4) {          // 7 load-pairs in flight per step
        u16x8 av[7], bv[7];
        #pragma unroll
        for (int i = 0; i < 7; ++i) {
          av[i] = ld16(arow + (c4 * 7 + i) * 32);
          bv[i] = ld16(brow + (c4 * 7 + i) * 32);
        }
        #pragma unroll
        for (int i = 0; i < 7; ++i) acc = mfma16(av[i], bv[i], acc);
      }
      #pragma unroll
      for (int r = 0; r < 4; ++r)       // C[m=s_local=quad*4+r][n=t_local=tcol]
        sims[tcol][wv * 16 + quad * 4 + r] = acc[r];
    }
  }
  __syncthreads();
  if (wv == 0) {
    u16x8 af0, af1;
    float lsum = 0.f;
    #pragma unroll
    for (int j = 0; j < 8; ++j) {
      {
        const int k = quad * 8 + j;                 // k in [0,32)
        const int dt = tcol + 32 - k;               // >= 1
        const int s = t0 - 32 + k;
        unsigned short wb = 0;
        if (dt < 32 && s >= 0)
          wb = f2bf(__expf(sims[tcol][k] * (__expf(-0.1f * (float)dt) * 0.033407657f)));
        af0[j] = wb;
        lsum += bf2f(wb);
      }
      {
        const int k = 32 + quad * 8 + j;            // k in [32,64)
        const int dt = tcol + 32 - k;               // <= 15
        unsigned short wb = 0;
        if (dt >= 0)                                // k <= tcol+32 <= 47
          wb = f2bf(__expf(sims[tcol][k] * (__expf(-0.1f * (float)dt) * 0.033407657f)));
        af1[j] = wb;
        lsum += bf2f(wb);
      }
    }
    lsum += __shfl_xor(lsum, 16, 64);
    lsum += __shfl_xor(lsum, 32, 64);
    st16(wband + (size_t)(t0 + tcol) * 64 + quad * 8, af0);
    st16(wband + (size_t)(t0 + tcol) * 64 + 32 + quad * 8, af1);
    if (lane < 16) {
      const int t = t0 + lane;
      invLb[t] = 1.0f / (lsum + ((t >= 32) ? (float)(t - 31) : 0.f));
    }
  }
}

// ---------- bandg: band GEMM (2048 blocks) + epilogue, no LDS ----------
__global__ __launch_bounds__(256) void k_bandg(const unsigned short* __restrict__ hbTp,
    const unsigned short* __restrict__ wband, const float* __restrict__ invLb,
    const float* __restrict__ P, const float* __restrict__ x,
    const float* __restrict__ invnorm, unsigned short* __restrict__ gb,
    float* __restrict__ gn2, float* __restrict__ dist2) {
  const int t0 = (int)blockIdx.x * 16;
  const int by = (int)blockIdx.y;             // 8 d-groups of 7 tiles
  const int tid = (int)threadIdx.x;
  const int wv = tid >> 6, lane = tid & 63;
  const int tcol = lane & 15, quad = lane >> 4;
  const u16x8 af0 = ld16(wband + (size_t)(t0 + tcol) * 64 + quad * 8);
  const u16x8 af1 = ld16(wband + (size_t)(t0 + tcol) * 64 + 32 + quad * 8);
  float invLr[4], inrr[4];
  #pragma unroll
  for (int r = 0; r < 4; ++r) {
    const int tt = t0 + quad * 4 + r;
    invLr[r] = invLb[tt];
    inrr[r]  = invnorm[tt];
  }
  float sgl[4] = {0.f, 0.f, 0.f, 0.f}, sdl[4] = {0.f, 0.f, 0.f, 0.f};
  for (int i = wv; i < 7; i += 4) {
    const int d = (by * 7 + i) * 16 + tcol;
    const unsigned short* brow = hbTp + (size_t)d * TP + t0 + quad * 8;
    const u16x8 b0 = ld16(brow);          // k in [0,32): zeros where s<0
    const u16x8 b1 = ld16(brow + 32);     // k in [32,64): tail x w=0 harmless
    f32x4 C = {};
    C = mfma16(af0, b0, C);
    C = mfma16(af1, b1, C);
    #pragma unroll
    for (int r = 0; r < 4; ++r) {     // C[m=quad*4+r -> t][n=tcol -> d]
      const int tt = t0 + quad * 4 + r;
      float gacc = C[r];
      if (tt >= 32) gacc += P[(size_t)(tt - 32) * D_ + d];
      const float g = gacc * invLr[r];
      gb[(size_t)tt * D_ + d] = f2bf(g);
      const float e = x[(size_t)tt * D_ + d] * inrr[r] - g;
      sgl[r] += g * g;
      sdl[r] += e * e;
    }
  }
  #pragma unroll
  for (int r = 0; r < 4; ++r) {
    float sg = sgl[r], sd = sdl[r];
    sg += __shfl_xor(sg, 1, 64); sg += __shfl_xor(sg, 2, 64);
    sg += __shfl_xor(sg, 4, 64); sg += __shfl_xor(sg, 8, 64);
    sd += __shfl_xor(sd, 1, 64); sd += __shfl_xor(sd, 2, 64);
    sd += __shfl_xor(sd, 4, 64); sd += __shfl_xor(sd, 8, 64);
    if (tcol == 0) {
      atomicAdd(&gn2[t0 + quad * 4 + r], sg);
      atomicAdd(&dist2[t0 + quad * 4 + r], sd);
    }
  }
}

// ---------- GEMM3: cross = g h^T (528 causal 128x128 tiles, BK=128); row-max ----------
__global__ __launch_bounds__(256, 2) void k_gemm3(const unsigned short* __restrict__ gb,
    const unsigned short* __restrict__ hb, const float* __restrict__ gn2,
    unsigned int* __restrict__ dmaxu) {
  int ti, sj;
  tri_decode((int)blockIdx.x, ti, sj);
  const int t0 = ti * 128, s0 = sj * 128;
  __shared__ unsigned short As[128 * 128];
  __shared__ unsigned short Bs[128 * 128];
  const int tid = (int)threadIdx.x;
  const int lane = tid & 63, wv = tid >> 6;
  const int wm = wv >> 1, wn = wv & 1;
  const int tcol = lane & 15, quad = lane >> 4;
  f32x4 acc[4][4] = {};
  for (int kc = 0; kc < 7; ++kc) {
    __syncthreads();
    stage_sw(gb + (size_t)t0 * D_ + kc * 128, D_, As, tid);
    stage_sw(hb + (size_t)s0 * D_ + kc * 128, D_, Bs, tid);
    __syncthreads();
    mfma_chunk(As, Bs, wm, wn, tcol, quad, acc);
  }
  #pragma unroll
  for (int mi = 0; mi < 4; ++mi) {
    #pragma unroll
    for (int r = 0; r < 4; ++r) {
      const int t = t0 + wm * 64 + mi * 16 + quad * 4 + r;
      const float gn = gn2[t];
      float m2 = 0.f;
      #pragma unroll
      for (int ni = 0; ni < 4; ++ni) {
        const int s = s0 + wn * 64 + ni * 16 + tcol;
        if (t - s >= 0)
          m2 = fmaxf(m2, fmaxf(1.0f - 2.0f * acc[mi][ni][r] + gn, 1e-24f));
      }
      m2 = fmaxf(m2, __shfl_xor(m2, 1, 64));
      m2 = fmaxf(m2, __shfl_xor(m2, 2, 64));
      m2 = fmaxf(m2, __shfl_xor(m2, 4, 64));
      m2 = fmaxf(m2, __shfl_xor(m2, 8, 64));
      if (tcol == 0) atomicMax(&dmaxu[t], __float_as_uint(m2));
    }
  }
}

__global__ __launch_bounds__(256) void k_final(const float* __restrict__ m_t,
    const float* __restrict__ c_t, const float* __restrict__ d_t,
    const float* __restrict__ mu, const float* __restrict__ dist2,
    const unsigned int* __restrict__ dmaxu, float* __restrict__ out) {
  const int t = (int)blockIdx.x * 256 + (int)threadIdx.x;
  if (t >= T_) return;
  float ratio;
  if (t == 0) {
    ratio = 0.f;  // ref: dist~1e-12, dist_max<1e-6 -> 1.0 => ratio ~0
  } else {
    float dmax = sqrtf(__uint_as_float(dmaxu[t]));
    if (dmax < 1e-6f) dmax = 1.0f;
    ratio = sqrtf(fmaxf(dist2[t], 1e-24f)) / (dmax + 1e-8f);
  }
  const float stab = 1.0f - 0.3f * c_t[t] + 0.2f * d_t[t];
  const float xi = 1.0f - mu[0] * m_t[t];
  out[t] = fminf(fmaxf(ratio * stab * xi, 0.f), 1.f);
}

extern "C" void kernel_launch(void* const* d_in, const int* in_sizes, int n_in,
                              void* d_out, int out_size, void* d_ws, size_t ws_size,
                              hipStream_t stream) {
  const float* x   = (const float*)d_in[0];
  const float* m_t = (const float*)d_in[1];
  const float* c_t = (const float*)d_in[2];
  const float* d_t = (const float*)d_in[3];
  const float* mu  = (const float*)d_in[4];
  float* out = (float*)d_out;

  float* ws = (float*)d_ws;
  float* invnorm = ws;                                          // [T]
  unsigned int* dmaxu = (unsigned int*)(ws + (size_t)T_);       // [T]
  float* gn2     = ws + 2 * (size_t)T_;                         // [T]
  float* dist2   = ws + 3 * (size_t)T_;                         // [T]
  float* invLb   = ws + 4 * (size_t)T_;                         // [T]
  float* Sseg    = ws + 5 * (size_t)T_;                         // [128*D]
  float* Eseg    = Sseg + 128 * (size_t)D_;                     // [128*D]
  float* P       = Eseg + 128 * (size_t)D_;                     // [T*D] fp32
  unsigned short* hb    = (unsigned short*)(P + (size_t)T_ * D_);  // [T*D]
  unsigned short* hbTp  = hb + (size_t)T_ * D_;                    // [D*(T+64)]
  unsigned short* gb    = hbTp + (size_t)D_ * TP;                  // [T*D]
  unsigned short* wband = gb + (size_t)T_ * D_;                    // [T*64]

  // zero dmaxu + gn2 + dist2 (contiguous 3T words)
  hipMemsetAsync(dmaxu, 0, 3 * (size_t)T_ * sizeof(unsigned int), stream);

  k_prep<<<T_, 256, 0, stream>>>(x, invnorm, hb);
  k_transp<<<dim3(T_ / 32, D_ / 32), 256, 0, stream>>>(hb, hbTp);
  k_sega<<<dim3(128, 4), 256, 0, stream>>>(hb, Sseg);
  k_segb<<<224, 256, 0, stream>>>(Sseg, Eseg);
  k_segc<<<dim3(128, 4), 64, 0, stream>>>(hb, Eseg, P);
  k_bandw<<<T_ / 16, 256, 0, stream>>>(hb, wband, invLb);
  k_bandg<<<dim3(T_ / 16, 8), 256, 0, stream>>>(hbTp, wband, invLb, P, x, invnorm,
                                                gb, gn2, dist2);
  k_gemm3<<<528, 256, 0, stream>>>(gb, hb, gn2, dmaxu);
  k_final<<<(T_ + 255) / 256, 256, 0, stream>>>(m_t, c_t, d_t, mu, dist2, dmaxu, out);
}